// Round 12
// baseline (50.251 us; speedup 1.0000x reference)
//
#include <hip/hip_runtime.h>
#include <cmath>

#define NPTS 12288
#define NB   64
#define NCH  9
#define NKC  10
#define NBLK 48          // blocks per batch (12288/256)
#define CAPB 24          // pool slots per (block, channel); Poisson(~4.2) => P(ovf)~1e-6/cell
#define TFIX 0.05f       // fixed gate: E[accepts] ~200 per (b,c); EXACT via fallbacks
#define BIGF 1000000.0f
typedef unsigned long long u64;

__device__ __forceinline__ float keyf(float x, float y, float z, float m) {
    float n2 = __fadd_rn(__fadd_rn(__fmul_rn(x, x), __fmul_rn(y, y)), __fmul_rn(z, z));
    return __fmul_rn(sqrtf(n2), m);
}

// ---------------------------------------------------------------------------
// K1: pure fixed-gate stream (unchanged from R11, best measured). Block = 256
// consecutive points; one thread = one point. seg first; unmasked lanes load
// their record; key < TFIX pushes packed u64 (keybits<<32|idx) into tiny LDS
// pools; coalesced dump. Exactness: >=10 keys < T => top-10 all < T => pool
// superset; else k2's full rescan (also on cell overflow) recomputes exactly.
// ---------------------------------------------------------------------------
__global__ __launch_bounds__(256)
void k1_gate(const float* __restrict__ kpts, const float* __restrict__ cpt,
             const float* __restrict__ seg,
             u64* __restrict__ du, int* __restrict__ cnt)
{
    const int blk = blockIdx.x % NBLK;
    const int b   = blockIdx.x / NBLK;
    const int t   = threadIdx.x;
    const int p0  = blk * 256;

    __shared__ int lcnt[NCH];
    __shared__ u64 lpd[NCH][CAPB];
    if (t < NCH) lcnt[t] = 0;
    __syncthreads();

    size_t base = (size_t)b * NPTS + p0 + t;
    float2 sg = *(const float2*)(seg + base * 2);
    if (sg.y > sg.x) {                         // argmax==1 <=> seg1>seg0
        float f[24];
        const float4* kp = (const float4*)(kpts + base * 24);
#pragma unroll
        for (int j = 0; j < 6; ++j) {
            float4 v = kp[j];
            f[4*j] = v.x; f[4*j+1] = v.y; f[4*j+2] = v.z; f[4*j+3] = v.w;
        }
        const float* cp = cpt + base * 3;
        float k[NCH];
#pragma unroll
        for (int c = 0; c < 8; ++c) k[c] = keyf(f[3*c], f[3*c+1], f[3*c+2], 1.0f);
        k[8] = keyf(cp[0], cp[1], cp[2], 1.0f);
#pragma unroll
        for (int c = 0; c < NCH; ++c) {
            if (k[c] < TFIX) {
                int sl = atomicAdd(&lcnt[c], 1);
                if (sl < CAPB)
                    lpd[c][sl] = ((u64)__float_as_uint(k[c]) << 32) | (unsigned)(p0 + t);
            }
        }
    }
    __syncthreads();

    // coalesced dump (cnt always written -> no workspace pre-zeroing needed)
    if (t < NCH * CAPB) {
        int c = t / CAPB, s = t % CAPB;
        int n = lcnt[c]; n = n > CAPB ? CAPB : n;
        size_t g = (((size_t)b * NCH + c) * NBLK + blk) * CAPB + s;
        if (s < n) du[g] = lpd[c][s];
    }
    if (t < NCH) cnt[((size_t)b * NCH + t) * NBLK + blk] = lcnt[t];  // raw (overflow flag)
}

// ---------------------------------------------------------------------------
// K2 (fused with SVD): one block per batch, 576 threads = 9 waves. Wave c
// runs the verified u64 scan of channel c's 48 cells (bounded predicated
// loads), exact (key,idx)-stable top-10 via sorted-insert + popmin, gather,
// bit-exact clustering -> voted[c] in LDS + kpts_voted out. One barrier,
// then thread 0 runs the verified Jacobi-Kabsch SVD (64 blocks in parallel
// across CUs). Full exact rescan per wave if cell overflow OR pool < 10.
// ---------------------------------------------------------------------------

#define JROT(P_, Q_) do {                                                      \
    float aa = G[0][P_]*G[0][P_] + G[1][P_]*G[1][P_] + G[2][P_]*G[2][P_];      \
    float bb = G[0][Q_]*G[0][Q_] + G[1][Q_]*G[1][Q_] + G[2][Q_]*G[2][Q_];      \
    float gg = G[0][P_]*G[0][Q_] + G[1][P_]*G[1][Q_] + G[2][P_]*G[2][Q_];      \
    if (fabsf(gg) > 1e-30f) {                                                  \
        float zeta = (bb - aa) / (2.0f * gg);                                  \
        float tt = copysignf(1.0f, zeta) / (fabsf(zeta) + sqrtf(1.0f + zeta*zeta)); \
        float cc = 1.0f / sqrtf(1.0f + tt * tt);                               \
        float ss = cc * tt;                                                    \
        _Pragma("unroll")                                                      \
        for (int ii = 0; ii < 3; ++ii) {                                       \
            float gp = G[ii][P_], gq = G[ii][Q_];                              \
            G[ii][P_] = cc*gp - ss*gq; G[ii][Q_] = ss*gp + cc*gq;              \
            float vp = Vv[ii][P_], vq = Vv[ii][Q_];                            \
            Vv[ii][P_] = cc*vp - ss*vq; Vv[ii][Q_] = ss*vp + cc*vq;            \
        }                                                                      \
    }                                                                          \
} while (0)

#define CSWAP(P_, Q_) do { if (s##P_ < s##Q_) {                                \
    float t_ = s##P_; s##P_ = s##Q_; s##Q_ = t_;                               \
    _Pragma("unroll")                                                          \
    for (int ii = 0; ii < 3; ++ii) {                                           \
        t_ = U[ii][P_];  U[ii][P_]  = U[ii][Q_];  U[ii][Q_]  = t_;             \
        t_ = Vv[ii][P_]; Vv[ii][P_] = Vv[ii][Q_]; Vv[ii][Q_] = t_;             \
    }                                                                          \
} } while (0)

__global__ __launch_bounds__(576)
void k2_fused(const float* __restrict__ pcld, const float* __restrict__ kpts,
              const float* __restrict__ cpt,  const float* __restrict__ seg,
              const float* __restrict__ mesh,
              const u64* __restrict__ du,     const int* __restrict__ cnt,
              float* __restrict__ out)
{
    const int b   = blockIdx.x;
    const int tid = threadIdx.x;
    const int c   = tid >> 6, lane = tid & 63;

    __shared__ float voted[NCH][3];

    int myc = (lane < NBLK) ? cnt[((size_t)b * NCH + c) * NBLK + lane] : 0;
    const bool ovf = __any(myc > CAPB);
    int mycl = myc > CAPB ? CAPB : myc;
    int tot = mycl;
#pragma unroll
    for (int d = 32; d; d >>= 1) tot += __shfl_xor(tot, d);
    const bool rescan = ovf || (tot < NKC);

    u64 v64[NKC];
#pragma unroll
    for (int j = 0; j < NKC; ++j) v64[j] = ~0ull;

    if (!rescan) {
        const size_t gb = ((size_t)b * NCH + c) * NBLK * CAPB;
#pragma unroll
        for (int kk = 0; kk < (NBLK * CAPB + 63) / 64; ++kk) {
            int e = lane + 64 * kk;
            int bk = e / CAPB, s = e % CAPB;
            int nbk = __shfl(mycl, bk);
            if (s < nbk) {
                u64 pk = du[gb + e];
                if (pk < v64[NKC-1]) {
                    v64[NKC-1] = pk;
#pragma unroll
                    for (int q = NKC - 1; q > 0; --q) {
                        if (v64[q] < v64[q-1]) { u64 tv = v64[q]; v64[q] = v64[q-1]; v64[q-1] = tv; }
                    }
                }
            }
        }
    } else {
        // exact fallback: full rescan of this channel incl. masked points
        for (int i = lane; i < NPTS; i += 64) {
            size_t base = (size_t)b * NPTS + i;
            float2 sg = *(const float2*)(seg + base * 2);
            float m = (sg.y > sg.x) ? 1.0f : BIGF;
            const float* op = (c < 8) ? (kpts + (base * 8 + c) * 3) : (cpt + base * 3);
            float x = keyf(op[0], op[1], op[2], m);
            u64 pk = ((u64)__float_as_uint(x) << 32) | (unsigned)i;
            if (pk < v64[NKC-1]) {
                v64[NKC-1] = pk;
#pragma unroll
                for (int q = NKC - 1; q > 0; --q) {
                    if (v64[q] < v64[q-1]) { u64 tv = v64[q]; v64[q] = v64[q-1]; v64[q-1] = tv; }
                }
            }
        }
    }

    // 10-round popmin; lane r keeps rank r (u64 order == (key,idx) stable)
    u64 keep = ~0ull;
#pragma unroll
    for (int r = 0; r < NKC; ++r) {
        u64 h = v64[0];
        u64 wm = h;
#pragma unroll
        for (int d = 32; d; d >>= 1) { u64 o = __shfl_xor(wm, d); wm = (o < wm) ? o : wm; }
        if (h == wm) {
#pragma unroll
            for (int q = 0; q < NKC - 1; ++q) v64[q] = v64[q + 1];
            v64[NKC - 1] = ~0ull;
        }
        if (lane == r) keep = wm;
    }
    const int keepi = (int)(unsigned)(keep & 0xffffffffull);

    float sx = 0.0f, sy = 0.0f, sz = 0.0f;
    if (lane < NKC) {
        size_t base = (size_t)b * NPTS + keepi;
        const float* pp = pcld + base * 3;
        const float* op = (c < 8) ? (kpts + (base * 8 + c) * 3) : (cpt + base * 3);
        sx = __fadd_rn(pp[0], op[0]);
        sy = __fadd_rn(pp[1], op[1]);
        sz = __fadd_rn(pp[2], op[2]);
    }

    float arr[NKC];
#pragma unroll
    for (int q = 0; q < NKC; ++q) {
        float ax = __shfl(sx, q), ay = __shfl(sy, q), az = __shfl(sz, q);
        arr[q] = (lane == 0) ? ax : (lane == 1) ? ay : az;
    }

    float sum = 0.0f;
#pragma unroll
    for (int q = 0; q < NKC; ++q) sum = __fadd_rn(sum, arr[q]);
    float mu = sum / 10.0f;
    float var = 0.0f;
#pragma unroll
    for (int q = 0; q < NKC; ++q) {
        float dq = __fsub_rn(arr[q], mu);
        var = __fadd_rn(var, __fmul_rn(dq, dq));
    }
    float sd = sqrtf(var / 10.0f);
    float fs = 0.0f; int cntk = 0;
#pragma unroll
    for (int q = 0; q < NKC; ++q) {
        float x = arr[q];
        if (fabsf(__fsub_rn(x, mu)) < sd) {
            fs = __fadd_rn(fs, x);
            if (x != 0.0f) cntk++;
        }
    }
    float res = fs / (float)(cntk > 0 ? cntk : 1);

    if (lane < 3) {
        voted[c][lane] = res;
        out[768 + ((size_t)b * NCH + c) * 3 + lane] = res;   // kpts_voted
    }
    __syncthreads();

    // ---- thread 0: Kabsch via 3x3 one-sided Jacobi SVD (verified) ----
    if (tid == 0) {
        float Ax[9], Ay[9], Az[9], Bx[9], By[9], Bz[9];
#pragma unroll
        for (int n = 0; n < 9; ++n) {
            const float* mp = mesh + ((size_t)b * 9 + n) * 3;
            Ax[n] = mp[0]; Ay[n] = mp[1]; Az[n] = mp[2];
            Bx[n] = voted[n][0]; By[n] = voted[n][1]; Bz[n] = voted[n][2];
        }
        float cax = 0, cay = 0, caz = 0, cbx = 0, cby = 0, cbz = 0;
#pragma unroll
        for (int n = 0; n < 9; ++n) {
            cax += Ax[n]; cay += Ay[n]; caz += Az[n];
            cbx += Bx[n]; cby += By[n]; cbz += Bz[n];
        }
        cax /= 9.0f; cay /= 9.0f; caz /= 9.0f;
        cbx /= 9.0f; cby /= 9.0f; cbz /= 9.0f;

        float H[3][3] = {{0,0,0},{0,0,0},{0,0,0}};
#pragma unroll
        for (int n = 0; n < 9; ++n) {
            float a0 = Ax[n]-cax, a1 = Ay[n]-cay, a2 = Az[n]-caz;
            float b0 = Bx[n]-cbx, b1 = By[n]-cby, b2 = Bz[n]-cbz;
            H[0][0]+=a0*b0; H[0][1]+=a0*b1; H[0][2]+=a0*b2;
            H[1][0]+=a1*b0; H[1][1]+=a1*b1; H[1][2]+=a1*b2;
            H[2][0]+=a2*b0; H[2][1]+=a2*b1; H[2][2]+=a2*b2;
        }

        float G[3][3], Vv[3][3];
#pragma unroll
        for (int i = 0; i < 3; ++i)
#pragma unroll
            for (int j = 0; j < 3; ++j) {
                G[i][j]  = H[i][j];
                Vv[i][j] = (i == j) ? 1.0f : 0.0f;
            }
        for (int sw = 0; sw < 8; ++sw) { JROT(0,1); JROT(0,2); JROT(1,2); }

        float s0 = sqrtf(G[0][0]*G[0][0] + G[1][0]*G[1][0] + G[2][0]*G[2][0]);
        float s1 = sqrtf(G[0][1]*G[0][1] + G[1][1]*G[1][1] + G[2][1]*G[2][1]);
        float s2 = sqrtf(G[0][2]*G[0][2] + G[1][2]*G[1][2] + G[2][2]*G[2][2]);
        float r0 = 1.0f / fmaxf(s0, 1e-30f);
        float r1 = 1.0f / fmaxf(s1, 1e-30f);
        float r2 = 1.0f / fmaxf(s2, 1e-30f);
        float U[3][3];
#pragma unroll
        for (int i = 0; i < 3; ++i) {
            U[i][0] = G[i][0] * r0; U[i][1] = G[i][1] * r1; U[i][2] = G[i][2] * r2;
        }
        CSWAP(0, 1); CSWAP(1, 2); CSWAP(0, 1);   // descending singular values

        float R0[3][3];
#pragma unroll
        for (int i = 0; i < 3; ++i)
#pragma unroll
            for (int j = 0; j < 3; ++j)
                R0[i][j] = Vv[i][0]*U[j][0] + Vv[i][1]*U[j][1] + Vv[i][2]*U[j][2];
        float det = R0[0][0]*(R0[1][1]*R0[2][2] - R0[1][2]*R0[2][1])
                  - R0[0][1]*(R0[1][0]*R0[2][2] - R0[1][2]*R0[2][0])
                  + R0[0][2]*(R0[1][0]*R0[2][1] - R0[1][1]*R0[2][0]);
        float dsgn = (det >= 0.0f) ? 1.0f : -1.0f;

        float R[3][3];
#pragma unroll
        for (int i = 0; i < 3; ++i)
#pragma unroll
            for (int j = 0; j < 3; ++j) {
                R[i][j] = Vv[i][0]*U[j][0] + Vv[i][1]*U[j][1] + dsgn*Vv[i][2]*U[j][2];
                out[(size_t)b * 9 + i * 3 + j] = R[i][j];
            }
#pragma unroll
        for (int i = 0; i < 3; ++i) {
            float ti = ((i==0)?cbx:(i==1)?cby:cbz)
                     - (R[i][0]*cax + R[i][1]*cay + R[i][2]*caz);
            out[576 + (size_t)b * 3 + i] = ti;
        }
    }
}

extern "C" void kernel_launch(void* const* d_in, const int* in_sizes, int n_in,
                              void* d_out, int out_size, void* d_ws, size_t ws_size,
                              hipStream_t stream)
{
    const float* pcld = (const float*)d_in[0];
    const float* kpts = (const float*)d_in[1];
    const float* cpt  = (const float*)d_in[2];
    const float* seg  = (const float*)d_in[3];
    const float* mesh = (const float*)d_in[4];
    float* out = (float*)d_out;

    // workspace: du [64*9*48*24] u64 | cnt [64*9*48] i
    const size_t poolN = (size_t)NB * NCH * NBLK * CAPB;
    u64* dup = (u64*)d_ws;
    int* cp_ = (int*)((char*)d_ws + poolN * sizeof(u64));

    k1_gate<<<NB * NBLK, 256, 0, stream>>>(kpts, cpt, seg, dup, cp_);
    k2_fused<<<NB, 576, 0, stream>>>(pcld, kpts, cpt, seg, mesh, dup, cp_, out);
}

// Round 13
// 40.102 us; speedup vs baseline: 1.2531x; 1.2531x over previous
//
#include <hip/hip_runtime.h>
#include <cmath>

#define NPTS 12288
#define NB   64
#define NCH  9
#define NKC  10
#define NBLK 24          // blocks per batch (12288/512)
#define CAPB 32          // pool slots per (block, channel); Poisson(~8.3) => P(ovf)~1e-10
#define TFIX 0.05f       // fixed gate: E[accepts] ~200 per (b,c); EXACT via fallbacks
#define BIGF 1000000.0f
typedef unsigned long long u64;

__device__ __forceinline__ float keyf(float x, float y, float z, float m) {
    float n2 = __fadd_rn(__fadd_rn(__fmul_rn(x, x), __fmul_rn(y, y)), __fmul_rn(z, z));
    return __fmul_rn(sqrtf(n2), m);
}

// ---------------------------------------------------------------------------
// K1: fixed-gate stream, 2 POINTS PER THREAD (R11 structure otherwise).
// One float4 seg load covers both points; each active point's record is 6
// independent float4 loads -> up to 13 outstanding misses per lane (vs 7),
// raising per-CU miss concurrency at the same occupancy. key < TFIX pushes
// packed u64 (keybits<<32|idx) into LDS pools; coalesced dump. Exactness:
// >=10 keys < T per (b,c) => top-10 all < T => pool superset; else k2's
// full rescan (also on cell overflow) recomputes exactly.
// ---------------------------------------------------------------------------
__global__ __launch_bounds__(256)
void k1_gate(const float* __restrict__ kpts, const float* __restrict__ cpt,
             const float* __restrict__ seg,
             u64* __restrict__ du, int* __restrict__ cnt)
{
    const int blk = blockIdx.x % NBLK;
    const int b   = blockIdx.x / NBLK;
    const int t   = threadIdx.x;
    const int p0  = blk * 512;

    __shared__ int lcnt[NCH];
    __shared__ u64 lpd[NCH][CAPB];
    if (t < NCH) lcnt[t] = 0;
    __syncthreads();

    const int i0 = p0 + 2 * t;                  // this thread's two points
    size_t base0 = (size_t)b * NPTS + i0;
    float4 sg = *(const float4*)(seg + base0 * 2);   // seg for i0 (x,y) and i0+1 (z,w)

#pragma unroll
    for (int pp = 0; pp < 2; ++pp) {
        const bool act = pp ? (sg.w > sg.z) : (sg.y > sg.x);   // argmax==1
        if (act) {
            size_t base = base0 + pp;
            float f[24];
            const float4* kp = (const float4*)(kpts + base * 24);
#pragma unroll
            for (int j = 0; j < 6; ++j) {
                float4 v = kp[j];
                f[4*j] = v.x; f[4*j+1] = v.y; f[4*j+2] = v.z; f[4*j+3] = v.w;
            }
            const float* cp = cpt + base * 3;
            float k[NCH];
#pragma unroll
            for (int c = 0; c < 8; ++c) k[c] = keyf(f[3*c], f[3*c+1], f[3*c+2], 1.0f);
            k[8] = keyf(cp[0], cp[1], cp[2], 1.0f);
#pragma unroll
            for (int c = 0; c < NCH; ++c) {
                if (k[c] < TFIX) {
                    int sl = atomicAdd(&lcnt[c], 1);
                    if (sl < CAPB)
                        lpd[c][sl] = ((u64)__float_as_uint(k[c]) << 32) | (unsigned)(i0 + pp);
                }
            }
        }
    }
    __syncthreads();

    // coalesced dump (cnt always written -> no workspace pre-zeroing needed)
    for (int e = t; e < NCH * CAPB; e += 256) {
        int c = e / CAPB, s = e % CAPB;
        int n = lcnt[c]; n = n > CAPB ? CAPB : n;
        size_t g = (((size_t)b * NCH + c) * NBLK + blk) * CAPB + s;
        if (s < n) du[g] = lpd[c][s];
    }
    if (t < NCH) cnt[((size_t)b * NCH + t) * NBLK + blk] = lcnt[t];  // raw (overflow flag)
}

// ---------------------------------------------------------------------------
// K2: one block per (b, c), 64 threads (1 wave). Packed-u64 scan of the 24
// cells (12 bounded steps); exact (key,idx)-stable top-10 via sorted-insert
// + popmin; gather; bit-exact clustering. Full exact rescan (incl. masked
// points) if any cell overflowed OR total pool < 10. (R11-verified)
// ---------------------------------------------------------------------------
__global__ __launch_bounds__(64)
void k2_select(const float* __restrict__ pcld, const float* __restrict__ kpts,
               const float* __restrict__ cpt,  const float* __restrict__ seg,
               const u64* __restrict__ du,     const int* __restrict__ cnt,
               float* __restrict__ vws,        float* __restrict__ out)
{
    const int bc = blockIdx.x;
    const int b  = bc / NCH, c = bc % NCH;
    const int lane = threadIdx.x;

    int myc = (lane < NBLK) ? cnt[((size_t)b * NCH + c) * NBLK + lane] : 0;
    const bool ovf = __any(myc > CAPB);
    int mycl = myc > CAPB ? CAPB : myc;
    int tot = mycl;
#pragma unroll
    for (int d = 32; d; d >>= 1) tot += __shfl_xor(tot, d);
    const bool rescan = ovf || (tot < NKC);

    u64 v64[NKC];
#pragma unroll
    for (int j = 0; j < NKC; ++j) v64[j] = ~0ull;

    if (!rescan) {
        const size_t gb = ((size_t)b * NCH + c) * NBLK * CAPB;
#pragma unroll
        for (int kk = 0; kk < (NBLK * CAPB + 63) / 64; ++kk) {
            int e = lane + 64 * kk;
            int bk = e / CAPB, s = e % CAPB;
            int nbk = __shfl(mycl, bk);
            if (s < nbk) {
                u64 pk = du[gb + e];
                if (pk < v64[NKC-1]) {
                    v64[NKC-1] = pk;
#pragma unroll
                    for (int q = NKC - 1; q > 0; --q) {
                        if (v64[q] < v64[q-1]) { u64 tv = v64[q]; v64[q] = v64[q-1]; v64[q-1] = tv; }
                    }
                }
            }
        }
    } else {
        // exact fallback: full rescan of this channel incl. masked points
        for (int i = lane; i < NPTS; i += 64) {
            size_t base = (size_t)b * NPTS + i;
            float2 sg = *(const float2*)(seg + base * 2);
            float m = (sg.y > sg.x) ? 1.0f : BIGF;
            const float* op = (c < 8) ? (kpts + (base * 8 + c) * 3) : (cpt + base * 3);
            float x = keyf(op[0], op[1], op[2], m);
            u64 pk = ((u64)__float_as_uint(x) << 32) | (unsigned)i;
            if (pk < v64[NKC-1]) {
                v64[NKC-1] = pk;
#pragma unroll
                for (int q = NKC - 1; q > 0; --q) {
                    if (v64[q] < v64[q-1]) { u64 tv = v64[q]; v64[q] = v64[q-1]; v64[q-1] = tv; }
                }
            }
        }
    }

    // 10-round popmin; lane r keeps rank r (u64 order == (key,idx) stable)
    u64 keep = ~0ull;
#pragma unroll
    for (int r = 0; r < NKC; ++r) {
        u64 h = v64[0];
        u64 wm = h;
#pragma unroll
        for (int d = 32; d; d >>= 1) { u64 o = __shfl_xor(wm, d); wm = (o < wm) ? o : wm; }
        if (h == wm) {
#pragma unroll
            for (int q = 0; q < NKC - 1; ++q) v64[q] = v64[q + 1];
            v64[NKC - 1] = ~0ull;
        }
        if (lane == r) keep = wm;
    }
    const int keepi = (int)(unsigned)(keep & 0xffffffffull);

    float sx = 0.0f, sy = 0.0f, sz = 0.0f;
    if (lane < NKC) {
        size_t base = (size_t)b * NPTS + keepi;
        const float* pp = pcld + base * 3;
        const float* op = (c < 8) ? (kpts + (base * 8 + c) * 3) : (cpt + base * 3);
        sx = __fadd_rn(pp[0], op[0]);
        sy = __fadd_rn(pp[1], op[1]);
        sz = __fadd_rn(pp[2], op[2]);
    }

    float arr[NKC];
#pragma unroll
    for (int q = 0; q < NKC; ++q) {
        float ax = __shfl(sx, q), ay = __shfl(sy, q), az = __shfl(sz, q);
        arr[q] = (lane == 0) ? ax : (lane == 1) ? ay : az;
    }

    float sum = 0.0f;
#pragma unroll
    for (int q = 0; q < NKC; ++q) sum = __fadd_rn(sum, arr[q]);
    float mu = sum / 10.0f;
    float var = 0.0f;
#pragma unroll
    for (int q = 0; q < NKC; ++q) {
        float dq = __fsub_rn(arr[q], mu);
        var = __fadd_rn(var, __fmul_rn(dq, dq));
    }
    float sd = sqrtf(var / 10.0f);
    float fs = 0.0f; int cntk = 0;
#pragma unroll
    for (int q = 0; q < NKC; ++q) {
        float x = arr[q];
        if (fabsf(__fsub_rn(x, mu)) < sd) {
            fs = __fadd_rn(fs, x);
            if (x != 0.0f) cntk++;
        }
    }
    float res = fs / (float)(cntk > 0 ? cntk : 1);

    if (lane < 3) {
        vws[(size_t)bc * 3 + lane] = res;
        out[768 + (size_t)bc * 3 + lane] = res;   // kpts_voted
    }
}

// ---------------------------------------------------------------------------
// K3: one block, 64 threads; lane b does batch b's whole Kabsch SVD in
// registers. (R11-verified)
// ---------------------------------------------------------------------------

#define JROT(P_, Q_) do {                                                      \
    float aa = G[0][P_]*G[0][P_] + G[1][P_]*G[1][P_] + G[2][P_]*G[2][P_];      \
    float bb = G[0][Q_]*G[0][Q_] + G[1][Q_]*G[1][Q_] + G[2][Q_]*G[2][Q_];      \
    float gg = G[0][P_]*G[0][Q_] + G[1][P_]*G[1][Q_] + G[2][P_]*G[2][Q_];      \
    if (fabsf(gg) > 1e-30f) {                                                  \
        float zeta = (bb - aa) / (2.0f * gg);                                  \
        float tt = copysignf(1.0f, zeta) / (fabsf(zeta) + sqrtf(1.0f + zeta*zeta)); \
        float cc = 1.0f / sqrtf(1.0f + tt * tt);                               \
        float ss = cc * tt;                                                    \
        _Pragma("unroll")                                                      \
        for (int ii = 0; ii < 3; ++ii) {                                       \
            float gp = G[ii][P_], gq = G[ii][Q_];                              \
            G[ii][P_] = cc*gp - ss*gq; G[ii][Q_] = ss*gp + cc*gq;              \
            float vp = Vv[ii][P_], vq = Vv[ii][Q_];                            \
            Vv[ii][P_] = cc*vp - ss*vq; Vv[ii][Q_] = ss*vp + cc*vq;            \
        }                                                                      \
    }                                                                          \
} while (0)

#define CSWAP(P_, Q_) do { if (s##P_ < s##Q_) {                                \
    float t_ = s##P_; s##P_ = s##Q_; s##Q_ = t_;                               \
    _Pragma("unroll")                                                          \
    for (int ii = 0; ii < 3; ++ii) {                                           \
        t_ = U[ii][P_];  U[ii][P_]  = U[ii][Q_];  U[ii][Q_]  = t_;             \
        t_ = Vv[ii][P_]; Vv[ii][P_] = Vv[ii][Q_]; Vv[ii][Q_] = t_;             \
    }                                                                          \
} } while (0)

__global__ __launch_bounds__(64)
void k3_svd(const float* __restrict__ mesh, const float* __restrict__ vws,
            float* __restrict__ out)
{
    const int b = threadIdx.x;   // one batch per lane

    float Ax[9], Ay[9], Az[9], Bx[9], By[9], Bz[9];
#pragma unroll
    for (int n = 0; n < 9; ++n) {
        const float* mp = mesh + ((size_t)b * 9 + n) * 3;
        Ax[n] = mp[0]; Ay[n] = mp[1]; Az[n] = mp[2];
        const float* vp = vws + ((size_t)b * 9 + n) * 3;
        Bx[n] = vp[0]; By[n] = vp[1]; Bz[n] = vp[2];
    }
    float cax = 0, cay = 0, caz = 0, cbx = 0, cby = 0, cbz = 0;
#pragma unroll
    for (int n = 0; n < 9; ++n) {
        cax += Ax[n]; cay += Ay[n]; caz += Az[n];
        cbx += Bx[n]; cby += By[n]; cbz += Bz[n];
    }
    cax /= 9.0f; cay /= 9.0f; caz /= 9.0f;
    cbx /= 9.0f; cby /= 9.0f; cbz /= 9.0f;

    float H[3][3] = {{0,0,0},{0,0,0},{0,0,0}};
#pragma unroll
    for (int n = 0; n < 9; ++n) {
        float a0 = Ax[n]-cax, a1 = Ay[n]-cay, a2 = Az[n]-caz;
        float b0 = Bx[n]-cbx, b1 = By[n]-cby, b2 = Bz[n]-cbz;
        H[0][0]+=a0*b0; H[0][1]+=a0*b1; H[0][2]+=a0*b2;
        H[1][0]+=a1*b0; H[1][1]+=a1*b1; H[1][2]+=a1*b2;
        H[2][0]+=a2*b0; H[2][1]+=a2*b1; H[2][2]+=a2*b2;
    }

    float G[3][3], Vv[3][3];
#pragma unroll
    for (int i = 0; i < 3; ++i)
#pragma unroll
        for (int j = 0; j < 3; ++j) {
            G[i][j]  = H[i][j];
            Vv[i][j] = (i == j) ? 1.0f : 0.0f;
        }
    for (int sw = 0; sw < 8; ++sw) { JROT(0,1); JROT(0,2); JROT(1,2); }

    float s0 = sqrtf(G[0][0]*G[0][0] + G[1][0]*G[1][0] + G[2][0]*G[2][0]);
    float s1 = sqrtf(G[0][1]*G[0][1] + G[1][1]*G[1][1] + G[2][1]*G[2][1]);
    float s2 = sqrtf(G[0][2]*G[0][2] + G[1][2]*G[1][2] + G[2][2]*G[2][2]);
    float r0 = 1.0f / fmaxf(s0, 1e-30f);
    float r1 = 1.0f / fmaxf(s1, 1e-30f);
    float r2 = 1.0f / fmaxf(s2, 1e-30f);
    float U[3][3];
#pragma unroll
    for (int i = 0; i < 3; ++i) {
        U[i][0] = G[i][0] * r0; U[i][1] = G[i][1] * r1; U[i][2] = G[i][2] * r2;
    }
    CSWAP(0, 1); CSWAP(1, 2); CSWAP(0, 1);   // descending singular values

    float R0[3][3];
#pragma unroll
    for (int i = 0; i < 3; ++i)
#pragma unroll
        for (int j = 0; j < 3; ++j)
            R0[i][j] = Vv[i][0]*U[j][0] + Vv[i][1]*U[j][1] + Vv[i][2]*U[j][2];
    float det = R0[0][0]*(R0[1][1]*R0[2][2] - R0[1][2]*R0[2][1])
              - R0[0][1]*(R0[1][0]*R0[2][2] - R0[1][2]*R0[2][0])
              + R0[0][2]*(R0[1][0]*R0[2][1] - R0[1][1]*R0[2][0]);
    float dsgn = (det >= 0.0f) ? 1.0f : -1.0f;

    float R[3][3];
#pragma unroll
    for (int i = 0; i < 3; ++i)
#pragma unroll
        for (int j = 0; j < 3; ++j) {
            R[i][j] = Vv[i][0]*U[j][0] + Vv[i][1]*U[j][1] + dsgn*Vv[i][2]*U[j][2];
            out[(size_t)b * 9 + i * 3 + j] = R[i][j];
        }
#pragma unroll
    for (int i = 0; i < 3; ++i) {
        float ti = ((i==0)?cbx:(i==1)?cby:cbz)
                 - (R[i][0]*cax + R[i][1]*cay + R[i][2]*caz);
        out[576 + (size_t)b * 3 + i] = ti;
    }
}

extern "C" void kernel_launch(void* const* d_in, const int* in_sizes, int n_in,
                              void* d_out, int out_size, void* d_ws, size_t ws_size,
                              hipStream_t stream)
{
    const float* pcld = (const float*)d_in[0];
    const float* kpts = (const float*)d_in[1];
    const float* cpt  = (const float*)d_in[2];
    const float* seg  = (const float*)d_in[3];
    const float* mesh = (const float*)d_in[4];
    float* out = (float*)d_out;

    // workspace: du [64*9*24*32] u64 | cnt [64*9*24] i | vws [64*9*3] f
    const size_t poolN = (size_t)NB * NCH * NBLK * CAPB;
    u64*   dup = (u64*)d_ws;
    int*   cp_ = (int*)((char*)d_ws + poolN * sizeof(u64));
    float* vws = (float*)((char*)d_ws + poolN * sizeof(u64) + (size_t)NB * NCH * NBLK * sizeof(int));

    k1_gate<<<NB * NBLK, 256, 0, stream>>>(kpts, cpt, seg, dup, cp_);
    k2_select<<<NB * NCH, 64, 0, stream>>>(pcld, kpts, cpt, seg, dup, cp_, vws, out);
    k3_svd<<<1, 64, 0, stream>>>(mesh, vws, out);
}

// Round 14
// 39.379 us; speedup vs baseline: 1.2761x; 1.0183x over previous
//
#include <hip/hip_runtime.h>
#include <cmath>

#define NPTS 12288
#define NB   64
#define NCH  9
#define NKC  10
#define NBLK 12          // blocks per batch (12288/1024)
#define CAPB 48          // pool slots per (block, channel); Poisson(~17) => P(ovf)~1e-10
#define TFIX 0.05f       // fixed gate: E[accepts] ~200 per (b,c); EXACT via fallbacks
#define BIGF 1000000.0f
typedef unsigned long long u64;

__device__ __forceinline__ float keyf(float x, float y, float z, float m) {
    float n2 = __fadd_rn(__fadd_rn(__fmul_rn(x, x), __fmul_rn(y, y)), __fmul_rn(z, z));
    return __fmul_rn(sqrtf(n2), m);
}

// ---------------------------------------------------------------------------
// K1: fixed-gate stream, 4 POINTS PER THREAD (R13 structure, deeper ILP).
// Two float4 seg loads cover four points; each active point's record is 6
// independent float4 loads -> up to ~26 outstanding misses per lane, raising
// per-CU miss concurrency at the same occupancy. key < TFIX pushes packed
// u64 (keybits<<32|idx) into LDS pools; coalesced dump. Exactness: >=10
// keys < T per (b,c) => top-10 all < T => pool superset; else k2's full
// rescan (also on cell overflow) recomputes exactly.
// ---------------------------------------------------------------------------
__global__ __launch_bounds__(256)
void k1_gate(const float* __restrict__ kpts, const float* __restrict__ cpt,
             const float* __restrict__ seg,
             u64* __restrict__ du, int* __restrict__ cnt)
{
    const int blk = blockIdx.x % NBLK;
    const int b   = blockIdx.x / NBLK;
    const int t   = threadIdx.x;
    const int p0  = blk * 1024;

    __shared__ int lcnt[NCH];
    __shared__ u64 lpd[NCH][CAPB];
    if (t < NCH) lcnt[t] = 0;
    __syncthreads();

    const int i0 = p0 + 4 * t;                  // this thread's four points
    size_t base0 = (size_t)b * NPTS + i0;
    float4 sgA = *(const float4*)(seg + base0 * 2);       // points i0, i0+1
    float4 sgB = *(const float4*)(seg + base0 * 2 + 4);   // points i0+2, i0+3

#pragma unroll
    for (int pp = 0; pp < 4; ++pp) {
        const bool act = (pp == 0) ? (sgA.y > sgA.x)
                       : (pp == 1) ? (sgA.w > sgA.z)
                       : (pp == 2) ? (sgB.y > sgB.x)
                                   : (sgB.w > sgB.z);     // argmax==1
        if (act) {
            size_t base = base0 + pp;
            float f[24];
            const float4* kp = (const float4*)(kpts + base * 24);
#pragma unroll
            for (int j = 0; j < 6; ++j) {
                float4 v = kp[j];
                f[4*j] = v.x; f[4*j+1] = v.y; f[4*j+2] = v.z; f[4*j+3] = v.w;
            }
            const float* cp = cpt + base * 3;
            float k[NCH];
#pragma unroll
            for (int c = 0; c < 8; ++c) k[c] = keyf(f[3*c], f[3*c+1], f[3*c+2], 1.0f);
            k[8] = keyf(cp[0], cp[1], cp[2], 1.0f);
#pragma unroll
            for (int c = 0; c < NCH; ++c) {
                if (k[c] < TFIX) {
                    int sl = atomicAdd(&lcnt[c], 1);
                    if (sl < CAPB)
                        lpd[c][sl] = ((u64)__float_as_uint(k[c]) << 32) | (unsigned)(i0 + pp);
                }
            }
        }
    }
    __syncthreads();

    // coalesced dump (cnt always written -> no workspace pre-zeroing needed)
    for (int e = t; e < NCH * CAPB; e += 256) {
        int c = e / CAPB, s = e % CAPB;
        int n = lcnt[c]; n = n > CAPB ? CAPB : n;
        size_t g = (((size_t)b * NCH + c) * NBLK + blk) * CAPB + s;
        if (s < n) du[g] = lpd[c][s];
    }
    if (t < NCH) cnt[((size_t)b * NCH + t) * NBLK + blk] = lcnt[t];  // raw (overflow flag)
}

// ---------------------------------------------------------------------------
// K2: one block per (b, c), 64 threads (1 wave). Packed-u64 scan of the 12
// cells (9 bounded steps); exact (key,idx)-stable top-10 via sorted-insert
// + popmin; gather; bit-exact clustering. Full exact rescan (incl. masked
// points) if any cell overflowed OR total pool < 10. (R11-verified)
// ---------------------------------------------------------------------------
__global__ __launch_bounds__(64)
void k2_select(const float* __restrict__ pcld, const float* __restrict__ kpts,
               const float* __restrict__ cpt,  const float* __restrict__ seg,
               const u64* __restrict__ du,     const int* __restrict__ cnt,
               float* __restrict__ vws,        float* __restrict__ out)
{
    const int bc = blockIdx.x;
    const int b  = bc / NCH, c = bc % NCH;
    const int lane = threadIdx.x;

    int myc = (lane < NBLK) ? cnt[((size_t)b * NCH + c) * NBLK + lane] : 0;
    const bool ovf = __any(myc > CAPB);
    int mycl = myc > CAPB ? CAPB : myc;
    int tot = mycl;
#pragma unroll
    for (int d = 32; d; d >>= 1) tot += __shfl_xor(tot, d);
    const bool rescan = ovf || (tot < NKC);

    u64 v64[NKC];
#pragma unroll
    for (int j = 0; j < NKC; ++j) v64[j] = ~0ull;

    if (!rescan) {
        const size_t gb = ((size_t)b * NCH + c) * NBLK * CAPB;
#pragma unroll
        for (int kk = 0; kk < (NBLK * CAPB + 63) / 64; ++kk) {
            int e = lane + 64 * kk;
            int bk = e / CAPB, s = e % CAPB;
            int nbk = __shfl(mycl, bk);
            if (s < nbk) {
                u64 pk = du[gb + e];
                if (pk < v64[NKC-1]) {
                    v64[NKC-1] = pk;
#pragma unroll
                    for (int q = NKC - 1; q > 0; --q) {
                        if (v64[q] < v64[q-1]) { u64 tv = v64[q]; v64[q] = v64[q-1]; v64[q-1] = tv; }
                    }
                }
            }
        }
    } else {
        // exact fallback: full rescan of this channel incl. masked points
        for (int i = lane; i < NPTS; i += 64) {
            size_t base = (size_t)b * NPTS + i;
            float2 sg = *(const float2*)(seg + base * 2);
            float m = (sg.y > sg.x) ? 1.0f : BIGF;
            const float* op = (c < 8) ? (kpts + (base * 8 + c) * 3) : (cpt + base * 3);
            float x = keyf(op[0], op[1], op[2], m);
            u64 pk = ((u64)__float_as_uint(x) << 32) | (unsigned)i;
            if (pk < v64[NKC-1]) {
                v64[NKC-1] = pk;
#pragma unroll
                for (int q = NKC - 1; q > 0; --q) {
                    if (v64[q] < v64[q-1]) { u64 tv = v64[q]; v64[q] = v64[q-1]; v64[q-1] = tv; }
                }
            }
        }
    }

    // 10-round popmin; lane r keeps rank r (u64 order == (key,idx) stable)
    u64 keep = ~0ull;
#pragma unroll
    for (int r = 0; r < NKC; ++r) {
        u64 h = v64[0];
        u64 wm = h;
#pragma unroll
        for (int d = 32; d; d >>= 1) { u64 o = __shfl_xor(wm, d); wm = (o < wm) ? o : wm; }
        if (h == wm) {
#pragma unroll
            for (int q = 0; q < NKC - 1; ++q) v64[q] = v64[q + 1];
            v64[NKC - 1] = ~0ull;
        }
        if (lane == r) keep = wm;
    }
    const int keepi = (int)(unsigned)(keep & 0xffffffffull);

    float sx = 0.0f, sy = 0.0f, sz = 0.0f;
    if (lane < NKC) {
        size_t base = (size_t)b * NPTS + keepi;
        const float* pp = pcld + base * 3;
        const float* op = (c < 8) ? (kpts + (base * 8 + c) * 3) : (cpt + base * 3);
        sx = __fadd_rn(pp[0], op[0]);
        sy = __fadd_rn(pp[1], op[1]);
        sz = __fadd_rn(pp[2], op[2]);
    }

    float arr[NKC];
#pragma unroll
    for (int q = 0; q < NKC; ++q) {
        float ax = __shfl(sx, q), ay = __shfl(sy, q), az = __shfl(sz, q);
        arr[q] = (lane == 0) ? ax : (lane == 1) ? ay : az;
    }

    float sum = 0.0f;
#pragma unroll
    for (int q = 0; q < NKC; ++q) sum = __fadd_rn(sum, arr[q]);
    float mu = sum / 10.0f;
    float var = 0.0f;
#pragma unroll
    for (int q = 0; q < NKC; ++q) {
        float dq = __fsub_rn(arr[q], mu);
        var = __fadd_rn(var, __fmul_rn(dq, dq));
    }
    float sd = sqrtf(var / 10.0f);
    float fs = 0.0f; int cntk = 0;
#pragma unroll
    for (int q = 0; q < NKC; ++q) {
        float x = arr[q];
        if (fabsf(__fsub_rn(x, mu)) < sd) {
            fs = __fadd_rn(fs, x);
            if (x != 0.0f) cntk++;
        }
    }
    float res = fs / (float)(cntk > 0 ? cntk : 1);

    if (lane < 3) {
        vws[(size_t)bc * 3 + lane] = res;
        out[768 + (size_t)bc * 3 + lane] = res;   // kpts_voted
    }
}

// ---------------------------------------------------------------------------
// K3: one block, 64 threads; lane b does batch b's whole Kabsch SVD in
// registers. (R11-verified)
// ---------------------------------------------------------------------------

#define JROT(P_, Q_) do {                                                      \
    float aa = G[0][P_]*G[0][P_] + G[1][P_]*G[1][P_] + G[2][P_]*G[2][P_];      \
    float bb = G[0][Q_]*G[0][Q_] + G[1][Q_]*G[1][Q_] + G[2][Q_]*G[2][Q_];      \
    float gg = G[0][P_]*G[0][Q_] + G[1][P_]*G[1][Q_] + G[2][P_]*G[2][Q_];      \
    if (fabsf(gg) > 1e-30f) {                                                  \
        float zeta = (bb - aa) / (2.0f * gg);                                  \
        float tt = copysignf(1.0f, zeta) / (fabsf(zeta) + sqrtf(1.0f + zeta*zeta)); \
        float cc = 1.0f / sqrtf(1.0f + tt * tt);                               \
        float ss = cc * tt;                                                    \
        _Pragma("unroll")                                                      \
        for (int ii = 0; ii < 3; ++ii) {                                       \
            float gp = G[ii][P_], gq = G[ii][Q_];                              \
            G[ii][P_] = cc*gp - ss*gq; G[ii][Q_] = ss*gp + cc*gq;              \
            float vp = Vv[ii][P_], vq = Vv[ii][Q_];                            \
            Vv[ii][P_] = cc*vp - ss*vq; Vv[ii][Q_] = ss*vp + cc*vq;            \
        }                                                                      \
    }                                                                          \
} while (0)

#define CSWAP(P_, Q_) do { if (s##P_ < s##Q_) {                                \
    float t_ = s##P_; s##P_ = s##Q_; s##Q_ = t_;                               \
    _Pragma("unroll")                                                          \
    for (int ii = 0; ii < 3; ++ii) {                                           \
        t_ = U[ii][P_];  U[ii][P_]  = U[ii][Q_];  U[ii][Q_]  = t_;             \
        t_ = Vv[ii][P_]; Vv[ii][P_] = Vv[ii][Q_]; Vv[ii][Q_] = t_;             \
    }                                                                          \
} } while (0)

__global__ __launch_bounds__(64)
void k3_svd(const float* __restrict__ mesh, const float* __restrict__ vws,
            float* __restrict__ out)
{
    const int b = threadIdx.x;   // one batch per lane

    float Ax[9], Ay[9], Az[9], Bx[9], By[9], Bz[9];
#pragma unroll
    for (int n = 0; n < 9; ++n) {
        const float* mp = mesh + ((size_t)b * 9 + n) * 3;
        Ax[n] = mp[0]; Ay[n] = mp[1]; Az[n] = mp[2];
        const float* vp = vws + ((size_t)b * 9 + n) * 3;
        Bx[n] = vp[0]; By[n] = vp[1]; Bz[n] = vp[2];
    }
    float cax = 0, cay = 0, caz = 0, cbx = 0, cby = 0, cbz = 0;
#pragma unroll
    for (int n = 0; n < 9; ++n) {
        cax += Ax[n]; cay += Ay[n]; caz += Az[n];
        cbx += Bx[n]; cby += By[n]; cbz += Bz[n];
    }
    cax /= 9.0f; cay /= 9.0f; caz /= 9.0f;
    cbx /= 9.0f; cby /= 9.0f; cbz /= 9.0f;

    float H[3][3] = {{0,0,0},{0,0,0},{0,0,0}};
#pragma unroll
    for (int n = 0; n < 9; ++n) {
        float a0 = Ax[n]-cax, a1 = Ay[n]-cay, a2 = Az[n]-caz;
        float b0 = Bx[n]-cbx, b1 = By[n]-cby, b2 = Bz[n]-cbz;
        H[0][0]+=a0*b0; H[0][1]+=a0*b1; H[0][2]+=a0*b2;
        H[1][0]+=a1*b0; H[1][1]+=a1*b1; H[1][2]+=a1*b2;
        H[2][0]+=a2*b0; H[2][1]+=a2*b1; H[2][2]+=a2*b2;
    }

    float G[3][3], Vv[3][3];
#pragma unroll
    for (int i = 0; i < 3; ++i)
#pragma unroll
        for (int j = 0; j < 3; ++j) {
            G[i][j]  = H[i][j];
            Vv[i][j] = (i == j) ? 1.0f : 0.0f;
        }
    for (int sw = 0; sw < 8; ++sw) { JROT(0,1); JROT(0,2); JROT(1,2); }

    float s0 = sqrtf(G[0][0]*G[0][0] + G[1][0]*G[1][0] + G[2][0]*G[2][0]);
    float s1 = sqrtf(G[0][1]*G[0][1] + G[1][1]*G[1][1] + G[2][1]*G[2][1]);
    float s2 = sqrtf(G[0][2]*G[0][2] + G[1][2]*G[1][2] + G[2][2]*G[2][2]);
    float r0 = 1.0f / fmaxf(s0, 1e-30f);
    float r1 = 1.0f / fmaxf(s1, 1e-30f);
    float r2 = 1.0f / fmaxf(s2, 1e-30f);
    float U[3][3];
#pragma unroll
    for (int i = 0; i < 3; ++i) {
        U[i][0] = G[i][0] * r0; U[i][1] = G[i][1] * r1; U[i][2] = G[i][2] * r2;
    }
    CSWAP(0, 1); CSWAP(1, 2); CSWAP(0, 1);   // descending singular values

    float R0[3][3];
#pragma unroll
    for (int i = 0; i < 3; ++i)
#pragma unroll
        for (int j = 0; j < 3; ++j)
            R0[i][j] = Vv[i][0]*U[j][0] + Vv[i][1]*U[j][1] + Vv[i][2]*U[j][2];
    float det = R0[0][0]*(R0[1][1]*R0[2][2] - R0[1][2]*R0[2][1])
              - R0[0][1]*(R0[1][0]*R0[2][2] - R0[1][2]*R0[2][0])
              + R0[0][2]*(R0[1][0]*R0[2][1] - R0[1][1]*R0[2][0]);
    float dsgn = (det >= 0.0f) ? 1.0f : -1.0f;

    float R[3][3];
#pragma unroll
    for (int i = 0; i < 3; ++i)
#pragma unroll
        for (int j = 0; j < 3; ++j) {
            R[i][j] = Vv[i][0]*U[j][0] + Vv[i][1]*U[j][1] + dsgn*Vv[i][2]*U[j][2];
            out[(size_t)b * 9 + i * 3 + j] = R[i][j];
        }
#pragma unroll
    for (int i = 0; i < 3; ++i) {
        float ti = ((i==0)?cbx:(i==1)?cby:cbz)
                 - (R[i][0]*cax + R[i][1]*cay + R[i][2]*caz);
        out[576 + (size_t)b * 3 + i] = ti;
    }
}

extern "C" void kernel_launch(void* const* d_in, const int* in_sizes, int n_in,
                              void* d_out, int out_size, void* d_ws, size_t ws_size,
                              hipStream_t stream)
{
    const float* pcld = (const float*)d_in[0];
    const float* kpts = (const float*)d_in[1];
    const float* cpt  = (const float*)d_in[2];
    const float* seg  = (const float*)d_in[3];
    const float* mesh = (const float*)d_in[4];
    float* out = (float*)d_out;

    // workspace: du [64*9*12*48] u64 | cnt [64*9*12] i | vws [64*9*3] f
    const size_t poolN = (size_t)NB * NCH * NBLK * CAPB;
    u64*   dup = (u64*)d_ws;
    int*   cp_ = (int*)((char*)d_ws + poolN * sizeof(u64));
    float* vws = (float*)((char*)d_ws + poolN * sizeof(u64) + (size_t)NB * NCH * NBLK * sizeof(int));

    k1_gate<<<NB * NBLK, 256, 0, stream>>>(kpts, cpt, seg, dup, cp_);
    k2_select<<<NB * NCH, 64, 0, stream>>>(pcld, kpts, cpt, seg, dup, cp_, vws, out);
    k3_svd<<<1, 64, 0, stream>>>(mesh, vws, out);
}